// Round 1
// baseline (2991.976 us; speedup 1.0000x reference)
//
#include <hip/hip_runtime.h>

#define DT 0.001f
#define GAMMA 2.0f

__global__ __launch_bounds__(256) void init_state(const float* __restrict__ init_pos,
                                                  float* __restrict__ x,
                                                  float* __restrict__ v,
                                                  int n_coords) {
    int i = blockIdx.x * blockDim.x + threadIdx.x;
    if (i < n_coords) { x[i] = init_pos[i]; v[i] = 0.0f; }
}

// One node per thread. Node j needs positions p[j-2..j+2], hinges j-2..j, edges j-1..j.
__global__ __launch_bounds__(256) void step_kernel(
    const float* __restrict__ xcur, float* __restrict__ xnext,
    float* __restrict__ vel,
    const float* __restrict__ init_pos,
    const int*   __restrict__ buckle,      // (H,4) int32
    const float* __restrict__ thetas_ss,   // (H,)
    const float* __restrict__ rest_len,    // (H+1,)
    const float* __restrict__ kstiff_p,
    const float* __restrict__ ksoft_p,
    const float* __restrict__ kstretch_p,
    float* __restrict__ out,               // d_out base
    int N, int H, int n_coords, int t, int n_steps)
{
    int j = blockIdx.x * blockDim.x + threadIdx.x;
    if (j >= N) return;

    const float kS  = kstiff_p[0];
    const float kw  = ksoft_p[0];
    const float kst = kstretch_p[0];

    // stage positions j-2 .. j+2 (clamped; out-of-range values are gated off below)
    float px[5], py[5];
    #pragma unroll
    for (int o = 0; o < 5; ++o) {
        int idx = j + o - 2;
        idx = idx < 0 ? 0 : (idx > N - 1 ? N - 1 : idx);
        px[o] = xcur[2 * idx];
        py[o] = xcur[2 * idx + 1];
    }

    // edges k=0..3  <-> global edge e = j-2+k (between nodes j-2+k, j-1+k)
    float ex[4], ey[4], len2[4];
    #pragma unroll
    for (int k = 0; k < 4; ++k) {
        ex[k] = px[k + 1] - px[k];
        ey[k] = py[k + 1] - py[k];
        len2[k] = ex[k] * ex[k] + ey[k] * ey[k];
    }

    // hinge torque scalars g for hinges i = j-2+k, k=0..2 (uses edges k, k+1)
    float g[3];
    #pragma unroll
    for (int k = 0; k < 3; ++k) {
        int i = j - 2 + k;
        if (i >= 0 && i < H) {
            float cr  = ex[k] * ey[k + 1] - ey[k] * ex[k + 1];
            float dt_ = ex[k] * ex[k + 1] + ey[k] * ey[k + 1];
            float th  = atan2f(cr, dt_);
            float tss = thetas_ss[i];
            int4 b = reinterpret_cast<const int4*>(buckle)[i];
            int ns = 0;
            ns += (b.x == 1) ? (th > -tss) : (th < tss);
            ns += (b.y == 1) ? (th > -tss) : (th < tss);
            ns += (b.z == 1) ? (th > -tss) : (th < tss);
            ns += (b.w == 1) ? (th > -tss) : (th < tss);
            float K = (float)ns * kS + (float)(4 - ns) * kw;
            g[k] = K * (th - tss);
        } else {
            g[k] = 0.0f;
        }
    }

    // F for edges e = j-1+m, m=0..1 (local edge index k=m+1; g_{e-1}=g[m], g_e=g[m+1])
    float Fx[2], Fy[2];
    #pragma unroll
    for (int m = 0; m < 2; ++m) {
        int e = j - 1 + m;
        int k = m + 1;
        if (e >= 0 && e <= H) {
            float il2 = 1.0f / len2[k];
            float l   = sqrtf(len2[k]);
            float coef = (g[m] - g[m + 1]) * il2;
            float s    = kst * (l - rest_len[e]) / l;
            Fx[m] = coef * (-ey[k]) + s * ex[k];
            Fy[m] = coef * ( ex[k]) + s * ey[k];
        } else {
            Fx[m] = 0.0f;
            Fy[m] = 0.0f;
        }
    }

    float fx = Fx[1] - Fx[0];
    float fy = Fy[1] - Fy[0];

    float vx = vel[2 * j], vy = vel[2 * j + 1];
    float xn_, yn_;
    if (j < 2) {
        vx = 0.0f; vy = 0.0f;
        xn_ = init_pos[2 * j];
        yn_ = init_pos[2 * j + 1];
    } else {
        vx += DT * (fx - GAMMA * vx);
        vy += DT * (fy - GAMMA * vy);
        xn_ = px[2] + DT * vx;
        yn_ = py[2] + DT * vy;
    }
    vel[2 * j] = vx;
    vel[2 * j + 1] = vy;
    xnext[2 * j] = xn_;
    xnext[2 * j + 1] = yn_;

    // trajectory output: d_out layout = [x_final (n_coords)] [pos_in_t (n_steps, n_coords)]
    float* row = out + (size_t)(t + 1) * (size_t)n_coords;
    row[2 * j] = xn_;
    row[2 * j + 1] = yn_;
    if (t == n_steps - 1) {
        out[2 * j] = xn_;
        out[2 * j + 1] = yn_;
    }
}

extern "C" void kernel_launch(void* const* d_in, const int* in_sizes, int n_in,
                              void* d_out, int out_size, void* d_ws, size_t ws_size,
                              hipStream_t stream) {
    const float* init_pos  = (const float*)d_in[0];
    const int*   buckle    = (const int*)d_in[1];
    const float* thetas_ss = (const float*)d_in[2];
    const float* rest_len  = (const float*)d_in[3];
    const float* kstiff    = (const float*)d_in[4];
    const float* ksoft     = (const float*)d_in[5];
    const float* kstretch  = (const float*)d_in[6];

    const int n_coords = in_sizes[0];       // 65540
    const int N = n_coords / 2;             // 32770 nodes
    const int H = in_sizes[2];              // 32768 hinges
    const int n_steps = out_size / n_coords - 1;  // 1000

    float* out = (float*)d_out;
    float* wsf = (float*)d_ws;
    float* xA  = wsf;
    float* xB  = wsf + n_coords;
    float* vel = wsf + 2 * n_coords;

    init_state<<<(n_coords + 255) / 256, 256, 0, stream>>>(init_pos, xA, vel, n_coords);

    float* xc = xA;
    float* xn = xB;
    for (int t = 0; t < n_steps; ++t) {
        step_kernel<<<(N + 255) / 256, 256, 0, stream>>>(
            xc, xn, vel, init_pos, buckle, thetas_ss, rest_len,
            kstiff, ksoft, kstretch, out, N, H, n_coords, t, n_steps);
        float* tmp = xc; xc = xn; xn = tmp;
    }
}

// Round 2
// 859.983 us; speedup vs baseline: 3.4791x; 3.4791x over previous
//
#include <hip/hip_runtime.h>

#define DT 0.001f
#define GAMMA 2.0f
#define TILE 256
#define HALO 128          // = 2*KSTEPS: dependency radius is 2 nodes/step
#define REGION 512        // TILE + 2*HALO
#define KSTEPS 64
#define NTHREADS 512      // 1 node/hinge/edge per thread

__global__ __launch_bounds__(256) void init_state(const float* __restrict__ init_pos,
                                                  float* __restrict__ x,
                                                  float* __restrict__ v,
                                                  int n_coords) {
    int i = blockIdx.x * blockDim.x + threadIdx.x;
    if (i < n_coords) { x[i] = init_pos[i]; v[i] = 0.0f; }
}

// Temporal-blocked chunk: each block owns TILE nodes, stages TILE+2*HALO into LDS,
// advances ksteps locally. Interior (tile) values are exact by the trapezoid
// argument: staleness/garbage propagates inward at 2 nodes/step from the region
// boundary, and HALO = 2*KSTEPS.
__global__ __launch_bounds__(NTHREADS) void chunk_kernel(
    const float* __restrict__ xin, const float* __restrict__ vin,
    float* __restrict__ xout, float* __restrict__ vout,
    const int*   __restrict__ buckle,      // (H,4) int32
    const float* __restrict__ thetas_ss,   // (H,)
    const float* __restrict__ rest_len,    // (H+1,)
    const float* __restrict__ kstiff_p,
    const float* __restrict__ ksoft_p,
    const float* __restrict__ kstretch_p,
    const float* __restrict__ init_pos,
    float* __restrict__ out,
    int N, int H, int n_coords, int t0, int ksteps, int n_steps)
{
    __shared__ float sx[REGION], sy[REGION];
    __shared__ float ex_s[REGION], ey_s[REGION], il2_s[REGION], se_s[REGION], g_s[REGION];

    const int tid = threadIdx.x;
    const int tile_start = blockIdx.x * TILE;
    const int tile_end   = min(tile_start + TILE, N);
    const int rs = max(tile_start - HALO, 0);
    const int re = min(tile_end + HALO, N);
    const int Rcur = re - rs;

    const float kS  = kstiff_p[0];
    const float kw  = ksoft_p[0];
    const float kst = kstretch_p[0];

    const int l  = tid;            // local node / edge / hinge index
    const int jg = rs + l;         // global node index
    const bool has_node  = (l < Rcur);
    const bool has_edge  = (l + 1 < Rcur);                 // edge (l, l+1), global e = jg <= N-2
    const bool has_hinge = (l + 2 < Rcur) && (jg < H);     // hinge jg uses edges jg, jg+1

    // chunk-constant per-thread data in registers
    float rl = 0.f, tss = 0.f, npf = 0.f;
    if (has_edge) rl = rest_len[jg];
    if (has_hinge) {
        tss = thetas_ss[jg];
        int4 b = reinterpret_cast<const int4*>(buckle)[jg];
        npf = (float)((b.x == 1) + (b.y == 1) + (b.z == 1) + (b.w == 1));
    }
    float vx = 0.f, vy = 0.f;
    if (has_node) {
        float2 p = reinterpret_cast<const float2*>(xin)[jg];
        sx[l] = p.x; sy[l] = p.y;
        float2 vv = reinterpret_cast<const float2*>(vin)[jg];
        vx = vv.x; vy = vv.y;
    }
    const bool interior = has_node && (jg >= tile_start) && (jg < tile_end);
    const bool pinned = has_node && (jg < 2);
    float pin_x = 0.f, pin_y = 0.f;
    if (pinned) { pin_x = init_pos[2 * jg]; pin_y = init_pos[2 * jg + 1]; }

    __syncthreads();

    for (int s = 0; s < ksteps; ++s) {
        // ---- Phase A: per-edge geometry + per-hinge torque scalar g ----
        if (has_edge) {
            float ax = sx[l],     ay = sy[l];
            float bx = sx[l + 1], by = sy[l + 1];
            float e_x = bx - ax, e_y = by - ay;
            float l2  = e_x * e_x + e_y * e_y;
            float len = sqrtf(l2);
            ex_s[l]  = e_x;
            ey_s[l]  = e_y;
            il2_s[l] = 1.0f / l2;
            se_s[l]  = kst * (len - rl) / len;
            float gv = 0.0f;
            if (has_hinge) {
                float cx = sx[l + 2] - bx, cy = sy[l + 2] - by;
                float cr = e_x * cy - e_y * cx;
                float dd = e_x * cx + e_y * cy;
                float th = atan2f(cr, dd);
                float ns = npf * (th > -tss ? 1.0f : 0.0f)
                         + (4.0f - npf) * (th < tss ? 1.0f : 0.0f);
                float K  = ns * kS + (4.0f - ns) * kw;
                gv = K * (th - tss);
            }
            g_s[l] = gv;
        } else {
            g_s[l] = 0.0f;   // l < REGION always (NTHREADS == REGION)
        }
        __syncthreads();

        // ---- Phase B: per-node force + integrate; write own pos in-place ----
        if (has_node) {
            float fx = 0.f, fy = 0.f;
            if (jg >= 1 && l >= 1) {               // edge j-1 (local l-1): F_prev, subtracted
                int le = l - 1;
                float gm   = (l >= 2) ? g_s[l - 2] : 0.0f;   // hinge j-2
                float coef = (gm - g_s[le]) * il2_s[le];
                float sc   = se_s[le];
                fx -= coef * (-ey_s[le]) + sc * ex_s[le];
                fy -= coef * ( ex_s[le]) + sc * ey_s[le];
            }
            if (jg < N - 1 && l + 1 < Rcur) {      // edge j (local l): F_cur, added
                float gm   = (l >= 1) ? g_s[l - 1] : 0.0f;   // hinge j-1
                float coef = (gm - g_s[l]) * il2_s[l];
                float sc   = se_s[l];
                fx += coef * (-ey_s[l]) + sc * ex_s[l];
                fy += coef * ( ex_s[l]) + sc * ey_s[l];
            }
            float nx, ny;
            if (pinned) {
                vx = 0.f; vy = 0.f; nx = pin_x; ny = pin_y;
            } else {
                vx += DT * (fx - GAMMA * vx);
                vy += DT * (fy - GAMMA * vy);
                nx = sx[l] + DT * vx;
                ny = sy[l] + DT * vy;
            }
            sx[l] = nx; sy[l] = ny;   // own-slot write; no cross-thread read in phase B
            if (interior) {
                float2* row = reinterpret_cast<float2*>(out + (size_t)(t0 + s + 1) * (size_t)n_coords);
                row[jg] = make_float2(nx, ny);
                if (t0 + s == n_steps - 1) {
                    reinterpret_cast<float2*>(out)[jg] = make_float2(nx, ny);  // x_final
                }
            }
        }
        __syncthreads();
    }

    // write interior state for next chunk (double-buffered across launches)
    if (interior) {
        reinterpret_cast<float2*>(xout)[jg] = make_float2(sx[l], sy[l]);
        reinterpret_cast<float2*>(vout)[jg] = make_float2(vx, vy);
    }
}

extern "C" void kernel_launch(void* const* d_in, const int* in_sizes, int n_in,
                              void* d_out, int out_size, void* d_ws, size_t ws_size,
                              hipStream_t stream) {
    const float* init_pos  = (const float*)d_in[0];
    const int*   buckle    = (const int*)d_in[1];
    const float* thetas_ss = (const float*)d_in[2];
    const float* rest_len  = (const float*)d_in[3];
    const float* kstiff    = (const float*)d_in[4];
    const float* ksoft     = (const float*)d_in[5];
    const float* kstretch  = (const float*)d_in[6];

    const int n_coords = in_sizes[0];             // 65540
    const int N = n_coords / 2;                   // 32770 nodes
    const int H = in_sizes[2];                    // 32768 hinges
    const int n_steps = out_size / n_coords - 1;  // 1000

    float* out = (float*)d_out;
    float* wsf = (float*)d_ws;
    float* sAx = wsf;
    float* sAv = wsf + n_coords;
    float* sBx = wsf + 2 * n_coords;
    float* sBv = wsf + 3 * n_coords;

    init_state<<<(n_coords + 255) / 256, 256, 0, stream>>>(init_pos, sAx, sAv, n_coords);

    const int nblocks = (N + TILE - 1) / TILE;    // 129
    float* xin = sAx; float* vin = sAv;
    float* xout = sBx; float* vout = sBv;
    for (int t0 = 0; t0 < n_steps; t0 += KSTEPS) {
        int k = n_steps - t0; if (k > KSTEPS) k = KSTEPS;
        chunk_kernel<<<nblocks, NTHREADS, 0, stream>>>(
            xin, vin, xout, vout,
            buckle, thetas_ss, rest_len, kstiff, ksoft, kstretch,
            init_pos, out, N, H, n_coords, t0, k, n_steps);
        float* t1 = xin; xin = xout; xout = t1;
        float* t2 = vin; vin = vout; vout = t2;
    }
}

// Round 3
// 841.037 us; speedup vs baseline: 3.5575x; 1.0225x over previous
//
#include <hip/hip_runtime.h>

#define DT 0.001f
#define GAMMA 2.0f
#define TILE 256
#define HALO 128          // = 2*KSTEPS: dependency radius is 2 nodes/step
#define REGION 512        // TILE + 2*HALO
#define KSTEPS 64
#define NTHREADS 512      // 1 node/hinge/edge per thread

// Relaxed workgroup barrier: drain LDS ops only (NOT vmcnt) + execution barrier.
// Trajectory stores to HBM are fire-and-forget (never read by device code), so
// draining them at every __syncthreads was pure stall. LDS visibility across
// waves needs only lgkmcnt(0) + s_barrier. Memory clobbers stop the compiler
// from moving DS ops across or caching LDS values in registers over the fence.
__device__ __forceinline__ void lds_barrier() {
    asm volatile("s_waitcnt lgkmcnt(0)" ::: "memory");
    __builtin_amdgcn_s_barrier();
    asm volatile("" ::: "memory");
}

__global__ __launch_bounds__(256) void init_state(const float* __restrict__ init_pos,
                                                  float* __restrict__ x,
                                                  float* __restrict__ v,
                                                  int n_coords) {
    int i = blockIdx.x * blockDim.x + threadIdx.x;
    if (i < n_coords) { x[i] = init_pos[i]; v[i] = 0.0f; }
}

// Temporal-blocked chunk: each block owns TILE nodes, stages TILE+2*HALO into LDS,
// advances ksteps locally. Interior (tile) values are exact by the trapezoid
// argument: staleness/garbage propagates inward at 2 nodes/step from the region
// boundary, and HALO = 2*KSTEPS.
__global__ __launch_bounds__(NTHREADS) void chunk_kernel(
    const float* __restrict__ xin, const float* __restrict__ vin,
    float* __restrict__ xout, float* __restrict__ vout,
    const int*   __restrict__ buckle,      // (H,4) int32
    const float* __restrict__ thetas_ss,   // (H,)
    const float* __restrict__ rest_len,    // (H+1,)
    const float* __restrict__ kstiff_p,
    const float* __restrict__ ksoft_p,
    const float* __restrict__ kstretch_p,
    const float* __restrict__ init_pos,
    float* __restrict__ out,
    int N, int H, int n_coords, int t0, int ksteps, int n_steps)
{
    __shared__ float sx[REGION], sy[REGION];
    __shared__ float ex_s[REGION], ey_s[REGION], il2_s[REGION], se_s[REGION], g_s[REGION];

    const int tid = threadIdx.x;
    const int tile_start = blockIdx.x * TILE;
    const int tile_end   = min(tile_start + TILE, N);
    const int rs = max(tile_start - HALO, 0);
    const int re = min(tile_end + HALO, N);
    const int Rcur = re - rs;

    const float kS  = kstiff_p[0];
    const float kw  = ksoft_p[0];
    const float kst = kstretch_p[0];

    const int l  = tid;            // local node / edge / hinge index
    const int jg = rs + l;         // global node index
    const bool has_node  = (l < Rcur);
    const bool has_edge  = (l + 1 < Rcur);                 // edge (l, l+1), global e = jg <= N-2
    const bool has_hinge = (l + 2 < Rcur) && (jg < H);     // hinge jg uses edges jg, jg+1

    // chunk-constant per-thread data in registers
    float rl = 0.f, tss = 0.f, npf = 0.f;
    if (has_edge) rl = rest_len[jg];
    if (has_hinge) {
        tss = thetas_ss[jg];
        int4 b = reinterpret_cast<const int4*>(buckle)[jg];
        npf = (float)((b.x == 1) + (b.y == 1) + (b.z == 1) + (b.w == 1));
    }
    float vx = 0.f, vy = 0.f;
    if (has_node) {
        float2 p = reinterpret_cast<const float2*>(xin)[jg];
        sx[l] = p.x; sy[l] = p.y;
        float2 vv = reinterpret_cast<const float2*>(vin)[jg];
        vx = vv.x; vy = vv.y;
    }
    const bool interior = has_node && (jg >= tile_start) && (jg < tile_end);
    const bool pinned = has_node && (jg < 2);
    float pin_x = 0.f, pin_y = 0.f;
    if (pinned) { pin_x = init_pos[2 * jg]; pin_y = init_pos[2 * jg + 1]; }

    lds_barrier();

    for (int s = 0; s < ksteps; ++s) {
        // ---- Phase A: per-edge geometry + per-hinge torque scalar g ----
        if (has_edge) {
            float ax = sx[l],     ay = sy[l];
            float bx = sx[l + 1], by = sy[l + 1];
            float e_x = bx - ax, e_y = by - ay;
            float l2  = e_x * e_x + e_y * e_y;
            float len = sqrtf(l2);
            ex_s[l]  = e_x;
            ey_s[l]  = e_y;
            il2_s[l] = 1.0f / l2;
            se_s[l]  = kst * (len - rl) / len;
            float gv = 0.0f;
            if (has_hinge) {
                float cx = sx[l + 2] - bx, cy = sy[l + 2] - by;
                float cr = e_x * cy - e_y * cx;
                float dd = e_x * cx + e_y * cy;
                float th = atan2f(cr, dd);
                float ns = npf * (th > -tss ? 1.0f : 0.0f)
                         + (4.0f - npf) * (th < tss ? 1.0f : 0.0f);
                float K  = ns * kS + (4.0f - ns) * kw;
                gv = K * (th - tss);
            }
            g_s[l] = gv;
        } else {
            g_s[l] = 0.0f;   // l < REGION always (NTHREADS == REGION)
        }
        lds_barrier();

        // ---- Phase B: per-node force + integrate; write own pos in-place ----
        if (has_node) {
            float fx = 0.f, fy = 0.f;
            if (jg >= 1 && l >= 1) {               // edge j-1 (local l-1): F_prev, subtracted
                int le = l - 1;
                float gm   = (l >= 2) ? g_s[l - 2] : 0.0f;   // hinge j-2
                float coef = (gm - g_s[le]) * il2_s[le];
                float sc   = se_s[le];
                fx -= coef * (-ey_s[le]) + sc * ex_s[le];
                fy -= coef * ( ex_s[le]) + sc * ey_s[le];
            }
            if (jg < N - 1 && l + 1 < Rcur) {      // edge j (local l): F_cur, added
                float gm   = (l >= 1) ? g_s[l - 1] : 0.0f;   // hinge j-1
                float coef = (gm - g_s[l]) * il2_s[l];
                float sc   = se_s[l];
                fx += coef * (-ey_s[l]) + sc * ex_s[l];
                fy += coef * ( ex_s[l]) + sc * ey_s[l];
            }
            float nx, ny;
            if (pinned) {
                vx = 0.f; vy = 0.f; nx = pin_x; ny = pin_y;
            } else {
                vx += DT * (fx - GAMMA * vx);
                vy += DT * (fy - GAMMA * vy);
                nx = sx[l] + DT * vx;
                ny = sy[l] + DT * vy;
            }
            sx[l] = nx; sy[l] = ny;   // own-slot write; no cross-thread read in phase B
            if (interior) {
                float2* row = reinterpret_cast<float2*>(out + (size_t)(t0 + s + 1) * (size_t)n_coords);
                row[jg] = make_float2(nx, ny);
                if (t0 + s == n_steps - 1) {
                    reinterpret_cast<float2*>(out)[jg] = make_float2(nx, ny);  // x_final
                }
            }
        }
        lds_barrier();
    }

    // write interior state for next chunk (double-buffered across launches)
    if (interior) {
        reinterpret_cast<float2*>(xout)[jg] = make_float2(sx[l], sy[l]);
        reinterpret_cast<float2*>(vout)[jg] = make_float2(vx, vy);
    }
}

extern "C" void kernel_launch(void* const* d_in, const int* in_sizes, int n_in,
                              void* d_out, int out_size, void* d_ws, size_t ws_size,
                              hipStream_t stream) {
    const float* init_pos  = (const float*)d_in[0];
    const int*   buckle    = (const int*)d_in[1];
    const float* thetas_ss = (const float*)d_in[2];
    const float* rest_len  = (const float*)d_in[3];
    const float* kstiff    = (const float*)d_in[4];
    const float* ksoft     = (const float*)d_in[5];
    const float* kstretch  = (const float*)d_in[6];

    const int n_coords = in_sizes[0];             // 65540
    const int N = n_coords / 2;                   // 32770 nodes
    const int H = in_sizes[2];                    // 32768 hinges
    const int n_steps = out_size / n_coords - 1;  // 1000

    float* out = (float*)d_out;
    float* wsf = (float*)d_ws;
    float* sAx = wsf;
    float* sAv = wsf + n_coords;
    float* sBx = wsf + 2 * n_coords;
    float* sBv = wsf + 3 * n_coords;

    init_state<<<(n_coords + 255) / 256, 256, 0, stream>>>(init_pos, sAx, sAv, n_coords);

    const int nblocks = (N + TILE - 1) / TILE;    // 129
    float* xin = sAx; float* vin = sAv;
    float* xout = sBx; float* vout = sBv;
    for (int t0 = 0; t0 < n_steps; t0 += KSTEPS) {
        int k = n_steps - t0; if (k > KSTEPS) k = KSTEPS;
        chunk_kernel<<<nblocks, NTHREADS, 0, stream>>>(
            xin, vin, xout, vout,
            buckle, thetas_ss, rest_len, kstiff, ksoft, kstretch,
            init_pos, out, N, H, n_coords, t0, k, n_steps);
        float* t1 = xin; xin = xout; xout = t1;
        float* t2 = vin; vin = vout; vout = t2;
    }
}

// Round 4
// 625.477 us; speedup vs baseline: 4.7835x; 1.3446x over previous
//
#include <hip/hip_runtime.h>

#define DT 0.001f
#define GAMMA 2.0f

#define KSTEPS 60         // steps per kernel launch
#define HALOB  120        // block halo = 2*KSTEPS (radius 2/step)
#define TILE   144        // interior nodes per block -> 228 blocks (<= 256 CUs, no straggler)
#define REGION 384        // TILE + 2*HALOB = NW*WINT
#define NW     8          // waves per block
#define WINT   48         // wave-interior nodes
#define WHALO  8          // wave halo per side = 2*JEXCH
#define JEXCH  4          // steps between intra-block LDS exchanges
#define NTHREADS 512

// LDS-only barrier: drain LDS/shfl ops, execution barrier. Global trajectory
// stores stay in flight (never read by device code).
__device__ __forceinline__ void lds_barrier() {
    asm volatile("s_waitcnt lgkmcnt(0)" ::: "memory");
    __builtin_amdgcn_s_barrier();
    asm volatile("" ::: "memory");
}

__global__ __launch_bounds__(256) void init_state(const float* __restrict__ init_pos,
                                                  float* __restrict__ x,
                                                  float* __restrict__ v,
                                                  int n_coords) {
    int i = blockIdx.x * blockDim.x + threadIdx.x;
    if (i < n_coords) { x[i] = init_pos[i]; v[i] = 0.0f; }
}

// Two-level temporal blocking:
//  - wave level: 1 node/lane, J=4 steps pure-shuffle (halo 8 lanes/side, radius 2/step)
//  - block level: 8 waves x 48 interior = REGION 384; LDS exchange every 4 steps
//  - grid level: TILE=144 exact for KSTEPS=60 with block halo 120
// Per-node arithmetic is expression-identical to the 2-phase LDS version, so
// interior trajectories are bit-identical.
__global__ __launch_bounds__(NTHREADS) void chunk_kernel(
    const float* __restrict__ xin, const float* __restrict__ vin,
    float* __restrict__ xout, float* __restrict__ vout,
    const int*   __restrict__ buckle,      // (H,4) int32
    const float* __restrict__ thetas_ss,   // (H,)
    const float* __restrict__ rest_len,    // (H+1,)
    const float* __restrict__ kstiff_p,
    const float* __restrict__ ksoft_p,
    const float* __restrict__ kstretch_p,
    const float* __restrict__ init_pos,
    float* __restrict__ out,
    int N, int H, int n_coords, int t0, int ksteps, int n_steps)
{
    __shared__ float4 xch[2][REGION];      // 12 KiB, double-buffered exchange

    const int lane = threadIdx.x & 63;
    const int w    = threadIdx.x >> 6;
    const int r    = w * WINT + lane - WHALO;           // region node (may be <0 or >=REGION)
    const int tile_start = blockIdx.x * TILE;
    const int jg   = tile_start - HALOB + r;            // global node
    const bool rvalid = (r >= 0) && (r < REGION);
    const bool nvalid = (jg >= 0) && (jg < N);
    const int  jc   = min(max(jg, 0), N - 1);           // clamped load index

    const float kS  = kstiff_p[0];
    const float kw  = ksoft_p[0];
    const float kst = kstretch_p[0];

    const bool edge_ok  = (jg >= 0) && (jg <= N - 2);
    const bool hinge_ok = (jg >= 0) && (jg < H);

    const float rl = rest_len[min(max(jg, 0), H)];
    float tss = 0.0f, npf = 0.0f;
    if (hinge_ok) {
        tss = thetas_ss[jg];
        int4 b = reinterpret_cast<const int4*>(buckle)[jg];
        npf = (float)((b.x == 1) + (b.y == 1) + (b.z == 1) + (b.w == 1));
    }
    const bool pinned = nvalid && (jg < 2);
    float pinx = 0.0f, piny = 0.0f;
    if (pinned) { pinx = init_pos[2 * jg]; piny = init_pos[2 * jg + 1]; }

    const bool wave_int = (lane >= WHALO) && (lane < WHALO + WINT);
    const bool writer   = wave_int && (r >= HALOB) && (r < HALOB + TILE) && nvalid;

    float2 P = reinterpret_cast<const float2*>(xin)[jc];
    float2 V = reinterpret_cast<const float2*>(vin)[jc];
    float px = P.x, py = P.y, vx = V.x, vy = V.y;

    float2* tptr = reinterpret_cast<float2*>(out + (size_t)(t0 + 1) * (size_t)n_coords) + jc;
    const int tstride = n_coords / 2;   // float2 elements per trajectory row

    for (int s = 0; s < ksteps; ++s) {
        // neighbor positions (in-register)
        float qx  = __shfl_down(px, 1), qy  = __shfl_down(py, 1);   // p_{j+1}
        float ux  = __shfl_down(px, 2), uy  = __shfl_down(py, 2);   // p_{j+2}

        // edge j
        float ex = qx - px, ey = qy - py;
        float l2 = ex * ex + ey * ey;
        float il2 = 1.0f / l2;
        float len = sqrtf(l2);
        float se  = kst * (len - rl) / len;

        // hinge j
        float cx = ux - qx, cy = uy - qy;                            // v_{j+1}
        float cr = ex * cy - ey * cx;
        float dd = ex * cx + ey * cy;
        float th = atan2f(cr, dd);
        float ns = npf * (th > -tss ? 1.0f : 0.0f)
                 + (4.0f - npf) * (th < tss ? 1.0f : 0.0f);
        float K  = ns * kS + (4.0f - ns) * kw;
        float g  = hinge_ok ? K * (th - tss) : 0.0f;

        // edge-j force (gated at source; shuffles propagate gated values)
        float gm   = __shfl_up(g, 1);                                // g_{j-1}
        float coef = (gm - g) * il2;
        float Fx = edge_ok ? coef * (-ey) + se * ex : 0.0f;
        float Fy = edge_ok ? coef * ( ex) + se * ey : 0.0f;
        float Fpx = __shfl_up(Fx, 1), Fpy = __shfl_up(Fy, 1);        // F_{j-1}

        float fx = Fx - Fpx;
        float fy = Fy - Fpy;

        vx += DT * (fx - GAMMA * vx);
        vy += DT * (fy - GAMMA * vy);
        px += DT * vx;
        py += DT * vy;
        if (pinned) { vx = 0.0f; vy = 0.0f; px = pinx; py = piny; }

        if (writer) { *tptr = make_float2(px, py); }
        tptr += tstride;

        // intra-block halo refresh every JEXCH steps (double-buffered: 1 barrier)
        if ((s & (JEXCH - 1)) == (JEXCH - 1) && (s + 1) < ksteps) {
            int buf = (s >> 2) & 1;
            if (wave_int && rvalid) xch[buf][r] = make_float4(px, py, vx, vy);
            lds_barrier();
            if (rvalid) {
                float4 f = xch[buf][r];
                px = f.x; py = f.y; vx = f.z; vy = f.w;
            }
        }
    }

    if (writer) {
        reinterpret_cast<float2*>(xout)[jg] = make_float2(px, py);
        reinterpret_cast<float2*>(vout)[jg] = make_float2(vx, vy);
        if (t0 + ksteps == n_steps) {
            reinterpret_cast<float2*>(out)[jg] = make_float2(px, py);  // x_final
        }
    }
}

extern "C" void kernel_launch(void* const* d_in, const int* in_sizes, int n_in,
                              void* d_out, int out_size, void* d_ws, size_t ws_size,
                              hipStream_t stream) {
    const float* init_pos  = (const float*)d_in[0];
    const int*   buckle    = (const int*)d_in[1];
    const float* thetas_ss = (const float*)d_in[2];
    const float* rest_len  = (const float*)d_in[3];
    const float* kstiff    = (const float*)d_in[4];
    const float* ksoft     = (const float*)d_in[5];
    const float* kstretch  = (const float*)d_in[6];

    const int n_coords = in_sizes[0];             // 65540
    const int N = n_coords / 2;                   // 32770 nodes
    const int H = in_sizes[2];                    // 32768 hinges
    const int n_steps = out_size / n_coords - 1;  // 1000

    float* out = (float*)d_out;
    float* wsf = (float*)d_ws;
    float* sAx = wsf;
    float* sAv = wsf + n_coords;
    float* sBx = wsf + 2 * n_coords;
    float* sBv = wsf + 3 * n_coords;

    init_state<<<(n_coords + 255) / 256, 256, 0, stream>>>(init_pos, sAx, sAv, n_coords);

    const int nblocks = (N + TILE - 1) / TILE;    // 228
    float* xin = sAx; float* vin = sAv;
    float* xout = sBx; float* vout = sBv;
    for (int t0 = 0; t0 < n_steps; t0 += KSTEPS) {
        int k = n_steps - t0; if (k > KSTEPS) k = KSTEPS;
        chunk_kernel<<<nblocks, NTHREADS, 0, stream>>>(
            xin, vin, xout, vout,
            buckle, thetas_ss, rest_len, kstiff, ksoft, kstretch,
            init_pos, out, N, H, n_coords, t0, k, n_steps);
        float* t1 = xin; xin = xout; xout = t1;
        float* t2 = vin; vin = vout; vout = t2;
    }
}

// Round 5
// 386.562 us; speedup vs baseline: 7.7400x; 1.6180x over previous
//
#include <hip/hip_runtime.h>

#define DT 0.001f
#define GAMMA 2.0f

#define KSTEPS 60         // steps per kernel launch
#define HALOB  120        // block halo = 2*KSTEPS (radius 2/step)
#define TILE   144        // interior nodes per block -> 228 blocks (<= 256 CUs)
#define REGION 384        // TILE + 2*HALOB = NW*WINT
#define NW     8          // waves per block
#define WINT   48         // wave-interior nodes
#define WHALO  8          // wave halo per side = 2*JEXCH
#define JEXCH  4          // steps between intra-block LDS exchanges
#define NTHREADS 512

// LDS-only barrier (global trajectory stores stay in flight).
__device__ __forceinline__ void lds_barrier() {
    asm volatile("s_waitcnt lgkmcnt(0)" ::: "memory");
    __builtin_amdgcn_s_barrier();
    asm volatile("" ::: "memory");
}

// DPP wave-wide shifts: VALU-latency cross-lane (vs ~100cy ds_bpermute).
// wave_shl:1 (0x130): lane i <- lane i+1  (== __shfl_down(x,1))
// wave_shr:1 (0x138): lane i <- lane i-1  (== __shfl_up(x,1))
// bound_ctrl=true: out-of-range lanes read 0 -> lands only in trapezoid halo.
__device__ __forceinline__ float dpp_shl1(float x) {
    return __int_as_float(__builtin_amdgcn_update_dpp(
        0, __float_as_int(x), 0x130, 0xF, 0xF, true));
}
__device__ __forceinline__ float dpp_shr1(float x) {
    return __int_as_float(__builtin_amdgcn_update_dpp(
        0, __float_as_int(x), 0x138, 0xF, 0xF, true));
}

// Minimax atan2 (A&S 4.4.49, |err| ~ 2e-8 over the reduced range).
// No special-case handling: inputs are edge cross/dot with |edge| ~ 1.
__device__ __forceinline__ float fast_atan2f(float y, float x) {
    float ax = fabsf(x), ay = fabsf(y);
    float mx = fmaxf(ax, ay), mn = fminf(ax, ay);
    float t  = mn * __builtin_amdgcn_rcpf(mx);
    float t2 = t * t;
    float p = -0.0040540580f;
    p = fmaf(p, t2,  0.0218612288f);
    p = fmaf(p, t2, -0.0559098861f);
    p = fmaf(p, t2,  0.0964200441f);
    p = fmaf(p, t2, -0.1390853351f);
    p = fmaf(p, t2,  0.1994653599f);
    p = fmaf(p, t2, -0.3332985605f);
    p = fmaf(p, t2,  0.9999993329f);
    float r = p * t;
    r = (ay > ax) ? (1.57079632679f - r) : r;
    r = (x < 0.0f) ? (3.14159265359f - r) : r;
    return copysignf(r, y);
}

__global__ __launch_bounds__(256) void init_state(const float* __restrict__ init_pos,
                                                  float* __restrict__ x,
                                                  float* __restrict__ v,
                                                  int n_coords) {
    int i = blockIdx.x * blockDim.x + threadIdx.x;
    if (i < n_coords) { x[i] = init_pos[i]; v[i] = 0.0f; }
}

// Two-level temporal blocking (structure identical to prev round); per-step
// math chain shortened: DPP shifts, minimax atan2, rsq instead of div/sqrt.
__global__ __launch_bounds__(NTHREADS) void chunk_kernel(
    const float* __restrict__ xin, const float* __restrict__ vin,
    float* __restrict__ xout, float* __restrict__ vout,
    const int*   __restrict__ buckle,      // (H,4) int32
    const float* __restrict__ thetas_ss,   // (H,)
    const float* __restrict__ rest_len,    // (H+1,)
    const float* __restrict__ kstiff_p,
    const float* __restrict__ ksoft_p,
    const float* __restrict__ kstretch_p,
    const float* __restrict__ init_pos,
    float* __restrict__ out,
    int N, int H, int n_coords, int t0, int ksteps, int n_steps)
{
    __shared__ float4 xch[2][REGION];      // 12 KiB, double-buffered exchange

    const int lane = threadIdx.x & 63;
    const int w    = threadIdx.x >> 6;
    const int r    = w * WINT + lane - WHALO;           // region node (may be OOB)
    const int tile_start = blockIdx.x * TILE;
    const int jg   = tile_start - HALOB + r;            // global node
    const bool rvalid = (r >= 0) && (r < REGION);
    const bool nvalid = (jg >= 0) && (jg < N);
    const int  jc   = min(max(jg, 0), N - 1);           // clamped load index

    const float kS  = kstiff_p[0];
    const float kw  = ksoft_p[0];
    const float kst = kstretch_p[0];

    const bool edge_ok  = (jg >= 0) && (jg <= N - 2);
    const bool hinge_ok = (jg >= 0) && (jg < H);

    const float rl    = rest_len[min(max(jg, 0), H)];
    const float kstrl = kst * rl;
    float tss = 0.0f, npf = 0.0f;
    if (hinge_ok) {
        tss = thetas_ss[jg];
        int4 b = reinterpret_cast<const int4*>(buckle)[jg];
        npf = (float)((b.x == 1) + (b.y == 1) + (b.z == 1) + (b.w == 1));
    }
    const bool pinned = nvalid && (jg < 2);
    float pinx = 0.0f, piny = 0.0f;
    if (pinned) { pinx = init_pos[2 * jg]; piny = init_pos[2 * jg + 1]; }

    const bool wave_int = (lane >= WHALO) && (lane < WHALO + WINT);
    const bool writer   = wave_int && (r >= HALOB) && (r < HALOB + TILE) && nvalid;

    float2 P = reinterpret_cast<const float2*>(xin)[jc];
    float2 V = reinterpret_cast<const float2*>(vin)[jc];
    float px = P.x, py = P.y, vx = V.x, vy = V.y;

    float2* tptr = reinterpret_cast<float2*>(out + (size_t)(t0 + 1) * (size_t)n_coords) + jc;
    const int tstride = n_coords / 2;   // float2 elements per trajectory row

    for (int s = 0; s < ksteps; ++s) {
        // neighbor positions via DPP (one hop, then chained hop for +2)
        float qx = dpp_shl1(px), qy = dpp_shl1(py);   // p_{j+1}
        float ux = dpp_shl1(qx), uy = dpp_shl1(qy);   // p_{j+2}

        // edge j
        float ex = qx - px, ey = qy - py;
        float l2 = ex * ex + ey * ey;
        float irt = __builtin_amdgcn_rsqf(l2);        // 1/len
        float il2 = irt * irt;                        // 1/len^2
        float se  = fmaf(-kstrl, irt, kst);           // kst*(len-rl)/len

        // hinge j
        float cx = ux - qx, cy = uy - qy;             // v_{j+1}
        float cr = ex * cy - ey * cx;
        float dd = ex * cx + ey * cy;
        float th = fast_atan2f(cr, dd);
        float ns = npf * (th > -tss ? 1.0f : 0.0f)
                 + (4.0f - npf) * (th < tss ? 1.0f : 0.0f);
        float K  = ns * kS + (4.0f - ns) * kw;
        float g  = hinge_ok ? K * (th - tss) : 0.0f;

        // edge-j force (gated at source; DPP propagates gated values)
        float gm   = dpp_shr1(g);                     // g_{j-1}
        float coef = (gm - g) * il2;
        float Fx = edge_ok ? coef * (-ey) + se * ex : 0.0f;
        float Fy = edge_ok ? coef * ( ex) + se * ey : 0.0f;
        float Fpx = dpp_shr1(Fx), Fpy = dpp_shr1(Fy); // F_{j-1}

        float fx = Fx - Fpx;
        float fy = Fy - Fpy;

        vx += DT * (fx - GAMMA * vx);
        vy += DT * (fy - GAMMA * vy);
        px += DT * vx;
        py += DT * vy;
        if (pinned) { vx = 0.0f; vy = 0.0f; px = pinx; py = piny; }

        if (writer) { *tptr = make_float2(px, py); }
        tptr += tstride;

        // intra-block halo refresh every JEXCH steps (double-buffered: 1 barrier)
        if ((s & (JEXCH - 1)) == (JEXCH - 1) && (s + 1) < ksteps) {
            int buf = (s >> 2) & 1;
            if (wave_int && rvalid) xch[buf][r] = make_float4(px, py, vx, vy);
            lds_barrier();
            if (rvalid) {
                float4 f = xch[buf][r];
                px = f.x; py = f.y; vx = f.z; vy = f.w;
            }
        }
    }

    if (writer) {
        reinterpret_cast<float2*>(xout)[jg] = make_float2(px, py);
        reinterpret_cast<float2*>(vout)[jg] = make_float2(vx, vy);
        if (t0 + ksteps == n_steps) {
            reinterpret_cast<float2*>(out)[jg] = make_float2(px, py);  // x_final
        }
    }
}

extern "C" void kernel_launch(void* const* d_in, const int* in_sizes, int n_in,
                              void* d_out, int out_size, void* d_ws, size_t ws_size,
                              hipStream_t stream) {
    const float* init_pos  = (const float*)d_in[0];
    const int*   buckle    = (const int*)d_in[1];
    const float* thetas_ss = (const float*)d_in[2];
    const float* rest_len  = (const float*)d_in[3];
    const float* kstiff    = (const float*)d_in[4];
    const float* ksoft     = (const float*)d_in[5];
    const float* kstretch  = (const float*)d_in[6];

    const int n_coords = in_sizes[0];             // 65540
    const int N = n_coords / 2;                   // 32770 nodes
    const int H = in_sizes[2];                    // 32768 hinges
    const int n_steps = out_size / n_coords - 1;  // 1000

    float* out = (float*)d_out;
    float* wsf = (float*)d_ws;
    float* sAx = wsf;
    float* sAv = wsf + n_coords;
    float* sBx = wsf + 2 * n_coords;
    float* sBv = wsf + 3 * n_coords;

    init_state<<<(n_coords + 255) / 256, 256, 0, stream>>>(init_pos, sAx, sAv, n_coords);

    const int nblocks = (N + TILE - 1) / TILE;    // 228
    float* xin = sAx; float* vin = sAv;
    float* xout = sBx; float* vout = sBv;
    for (int t0 = 0; t0 < n_steps; t0 += KSTEPS) {
        int k = n_steps - t0; if (k > KSTEPS) k = KSTEPS;
        chunk_kernel<<<nblocks, NTHREADS, 0, stream>>>(
            xin, vin, xout, vout,
            buckle, thetas_ss, rest_len, kstiff, ksoft, kstretch,
            init_pos, out, N, H, n_coords, t0, k, n_steps);
        float* t1 = xin; xin = xout; xout = t1;
        float* t2 = vin; vin = vout; vout = t2;
    }
}